// Round 6
// baseline (2059.428 us; speedup 1.0000x reference)
//
#include <hip/hip_runtime.h>
#include <hip/hip_bf16.h>

#define TT 12
#define HDIM 128
#define ODIM 12
#define MBX 128        // LSTM nodes per block
#define KS 136         // hA row stride in shorts (272 B; 0 bank conflicts measured in R4)
#define TPAD 36        // fp32 GCN gemm LDS pad

typedef short bf16x8 __attribute__((ext_vector_type(8)));
typedef float f32x16 __attribute__((ext_vector_type(16)));

__device__ __forceinline__ float fastrcp(float x) { return __builtin_amdgcn_rcpf(x); }
__device__ __forceinline__ float sigf(float x) { return fastrcp(1.f + __expf(-x)); }
__device__ __forceinline__ float tanh_fast(float x) { return 1.f - 2.f * fastrcp(1.f + __expf(2.f * x)); }
__device__ __forceinline__ unsigned short f2bf(float f) {
    union { float f; unsigned int u; } v; v.f = f;
    unsigned int r = v.u + 0x7FFFu + ((v.u >> 16) & 1u);
    return (unsigned short)(r >> 16);
}

// ---------------- weight pre-pack into MFMA B-fragment order ----------------
// K=128 for all 3 matrices. slot = (mat*16 + cb)*8 + s  (384 slots x 1 KB = 384 KB)
// element = Wpk[(slot*64 + lane)*8 + j];  B[k][col]: col=cb*32+(lane&31), k=s*16+(lane>>5)*8+j
__global__ void pack_kernel(const float* __restrict__ Whh0, const float* __restrict__ Wih1,
                            const float* __restrict__ Whh1, unsigned short* __restrict__ Wpk)
{
    int idx = blockIdx.x * 256 + threadIdx.x;
    if (idx >= 384 * 64) return;
    int lane = idx & 63;
    int slot = idx >> 6;
    int mat = slot >> 7;
    int rem = slot & 127;
    int cb = rem >> 3, s = rem & 7;
    int col = cb * 32 + (lane & 31);
    const float* src = (mat == 0) ? Whh0 : (mat == 1) ? Wih1 : Whh1;
#pragma unroll
    for (int j = 0; j < 8; ++j) {
        int k = s * 16 + ((lane >> 5) << 3) + j;
        Wpk[((size_t)(slot * 64 + lane) << 3) + j] = f2bf(src[col * 128 + k]);
    }
}

// ---------------- fused 2-layer LSTM, bf16 MFMA, 4-wave blocks ----------------
// wave w owns channel-group w: cb = g*4+w for g=0..3; covers ALL 128 nodes (4 row-blocks).
__device__ __forceinline__ void gemm8(const unsigned short* __restrict__ hA,
                                      const unsigned short* __restrict__ Wm,
                                      int w, int ln, f32x16 (&acc)[4][4])
{
    const int ln31 = ln & 31, half = ln >> 5;
#pragma unroll
    for (int s = 0; s < 8; ++s) {
        bf16x8 a[4];
#pragma unroll
        for (int rb = 0; rb < 4; ++rb)
            a[rb] = *(const bf16x8*)(hA + (rb * 32 + ln31) * KS + s * 16 + half * 8);
#pragma unroll
        for (int g = 0; g < 4; ++g) {
            int cb = g * 4 + w;
            bf16x8 b = *(const bf16x8*)(Wm + (((cb * 8 + s) * 64 + ln) << 3));
#pragma unroll
            for (int rb = 0; rb < 4; ++rb)
                acc[rb][g] = __builtin_amdgcn_mfma_f32_32x32x16_bf16(a[rb], b, acc[rb][g], 0, 0, 0);
        }
    }
}

__device__ __forceinline__ void zero_acc(f32x16 (&acc)[4][4])
{
#pragma unroll
    for (int rb = 0; rb < 4; ++rb)
#pragma unroll
        for (int g = 0; g < 4; ++g)
#pragma unroll
            for (int e = 0; e < 16; ++e) acc[rb][g][e] = 0.f;
}

__global__ __launch_bounds__(256, 1) void lstm_mfma_kernel(
    const float* __restrict__ x,              // [N][12][2]
    const unsigned short* __restrict__ Wpk,   // packed B fragments (384 KB)
    const float* __restrict__ Wih0,           // [512][2]
    const float* __restrict__ bih0, const float* __restrict__ bhh0,
    const float* __restrict__ bih1, const float* __restrict__ bhh1,
    float* __restrict__ hbuf,                 // [N][128] out (fp32 h1 at t=11)
    int N)
{
    __shared__ unsigned short hA0[MBX * KS];  // 34.8 KB
    __shared__ unsigned short hA1[MBX * KS];  // 34.8 KB
    __shared__ float cls0[MBX * HDIM];        // 64 KB layer-0 c-state
    __shared__ float xls[MBX * TT * 2];       // 12.3 KB

    const int tid  = threadIdx.x;
    const int w    = tid >> 6;     // wave = channel group 0..3
    const int ln   = tid & 63;
    const int ln31 = ln & 31;
    const int half = ln >> 5;
    const int col  = w * 32 + ln31;           // output channel 0..127
    const int nbase = blockIdx.x * MBX;

    // stage x (coalesced fp32)
    for (int i = tid; i < MBX * TT * 2; i += 256) {
        int n = nbase + i / (TT * 2);
        xls[i] = (n < N) ? x[(size_t)nbase * (TT * 2) + i] : 0.f;
    }
    for (int i = tid; i < MBX * KS; i += 256) { hA0[i] = 0; hA1[i] = 0; }
    for (int i = tid; i < MBX * HDIM; i += 256) cls0[i] = 0.f;

    // per-thread gate constants for channel `col` (4 gates)
    float wx0[4], wx1[4], br0[4], br1[4];
#pragma unroll
    for (int g = 0; g < 4; ++g) {
        int row = (g << 7) + col;
        wx0[g] = Wih0[row * 2 + 0];
        wx1[g] = Wih0[row * 2 + 1];
        br0[g] = bih0[row] + bhh0[row];
        br1[g] = bih1[row] + bhh1[row];
    }

    float c1[4][16];
#pragma unroll
    for (int rb = 0; rb < 4; ++rb)
#pragma unroll
        for (int r = 0; r < 16; ++r) c1[rb][r] = 0.f;

    __syncthreads();

    const unsigned short* Wm0 = Wpk;            // Whh0
    const unsigned short* Wm1 = Wpk + 65536;    // Wih1
    const unsigned short* Wm2 = Wpk + 131072;   // Whh1

    for (int t = 0; t < TT; ++t) {
        // ---- layer 0: z0 = h0_{t-1} @ Whh0^T (+ x/bias in epilogue) ----
        f32x16 acc[4][4];
        zero_acc(acc);
        gemm8(hA0, Wm0, w, ln, acc);
        __syncthreads();   // B1: all GEMM0 reads of hA0 done

#pragma unroll
        for (int rb = 0; rb < 4; ++rb) {
#pragma unroll
            for (int r = 0; r < 16; ++r) {
                int node = rb * 32 + (r & 3) + 8 * (r >> 2) + 4 * half;
                float xa = xls[node * (TT * 2) + t * 2 + 0];
                float xb = xls[node * (TT * 2) + t * 2 + 1];
                float zi = acc[rb][0][r] + br0[0] + wx0[0] * xa + wx1[0] * xb;
                float zf = acc[rb][1][r] + br0[1] + wx0[1] * xa + wx1[1] * xb;
                float zg = acc[rb][2][r] + br0[2] + wx0[2] * xa + wx1[2] * xb;
                float zo = acc[rb][3][r] + br0[3] + wx0[3] * xa + wx1[3] * xb;
                float cp = cls0[node * HDIM + col];     // cell owned by this thread only
                float cn = sigf(zf) * cp + sigf(zi) * tanh_fast(zg);
                cls0[node * HDIM + col] = cn;
                float h = sigf(zo) * tanh_fast(cn);
                hA0[node * KS + col] = f2bf(h);         // in-place: reads done at B1
            }
        }
        __syncthreads();   // B2: h0_t visible

        // ---- layer 1: z1 = h0_t @ Wih1^T + h1_{t-1} @ Whh1^T ----
        zero_acc(acc);
        gemm8(hA0, Wm1, w, ln, acc);
        gemm8(hA1, Wm2, w, ln, acc);
        __syncthreads();   // B3: all GEMM1 reads of hA1 done

#pragma unroll
        for (int rb = 0; rb < 4; ++rb) {
#pragma unroll
            for (int r = 0; r < 16; ++r) {
                int node = rb * 32 + (r & 3) + 8 * (r >> 2) + 4 * half;
                float zi = acc[rb][0][r] + br1[0];
                float zf = acc[rb][1][r] + br1[1];
                float zg = acc[rb][2][r] + br1[2];
                float zo = acc[rb][3][r] + br1[3];
                float cn = sigf(zf) * c1[rb][r] + sigf(zi) * tanh_fast(zg);
                c1[rb][r] = cn;
                float h = sigf(zo) * tanh_fast(cn);
                if (t + 1 < TT) {
                    hA1[node * KS + col] = f2bf(h);     // in-place: reads done at B3
                } else {
                    int n = nbase + node;
                    if (n < N) hbuf[n * HDIM + col] = h;
                }
            }
        }
        // ordering across t: epi1's hA1 writes vs next GEMM1 reads separated by next B1+B2;
        // next epi0's hA0 writes vs this GEMM1's hA0 reads separated by B3.
    }
}

// ---------------- GCN (unchanged this round) ----------------
__global__ void deg_count_kernel(const int* __restrict__ ei, int* __restrict__ degi, int E)
{
    int e = blockIdx.x * 256 + threadIdx.x;
    if (e < E) atomicAdd(&degi[ei[E + e]], 1);
}

__global__ void row_alloc_kernel(const int* __restrict__ degi, int* __restrict__ row_ptr,
                                 float* __restrict__ dinv, int* __restrict__ counter, int N)
{
    int n = blockIdx.x * 256 + threadIdx.x;
    int lane = threadIdx.x & 63;
    int v = (n < N) ? degi[n] : 0;
    int incl = v;
    for (int off = 1; off < 64; off <<= 1) {
        int u = __shfl_up(incl, off);
        if (lane >= off) incl += u;
    }
    int base = 0;
    if (lane == 63) base = atomicAdd(counter, incl);
    base = __shfl(base, 63);
    if (n < N) {
        row_ptr[n] = base + (incl - v);
        dinv[n] = rsqrtf((float)(v + 1));
    }
}

__global__ void csr_fill_kernel(const int* __restrict__ ei, const int* __restrict__ row_ptr,
                                int* __restrict__ fill, int* __restrict__ csr_src, int E)
{
    int e = blockIdx.x * 256 + threadIdx.x;
    if (e < E) {
        int d = ei[E + e];
        int p = atomicAdd(&fill[d], 1);
        csr_src[row_ptr[d] + p] = ei[e];
    }
}

__global__ __launch_bounds__(256) void gemm128_kernel(const float* __restrict__ X,
                                                      const float* __restrict__ W,
                                                      float* __restrict__ Y, int N)
{
    __shared__ float XT[128 * TPAD];
    const int tid = threadIdx.x;
    const int nbase = blockIdx.x * 32;
    for (int idx = tid; idx < 32 * 128; idx += 256) {
        int m = idx >> 7, k = idx & 127;
        int n = nbase + m;
        XT[k * TPAD + m] = (n < N) ? X[n * HDIM + k] : 0.f;
    }
    __syncthreads();
    const int c  = tid & 63;
    const int mb = (tid >> 6) << 3;
    float acc[8][2];
#pragma unroll
    for (int i = 0; i < 8; ++i) { acc[i][0] = 0.f; acc[i][1] = 0.f; }
    for (int k = 0; k < 128; ++k) {
        const float* xr = &XT[k * TPAD + mb];
        float4 a0 = *(const float4*)(xr);
        float4 a1 = *(const float4*)(xr + 4);
        float a[8] = {a0.x, a0.y, a0.z, a0.w, a1.x, a1.y, a1.z, a1.w};
        float b0 = W[k * HDIM + c];
        float b1 = W[k * HDIM + c + 64];
#pragma unroll
        for (int i = 0; i < 8; ++i) {
            acc[i][0] = fmaf(a[i], b0, acc[i][0]);
            acc[i][1] = fmaf(a[i], b1, acc[i][1]);
        }
    }
#pragma unroll
    for (int i = 0; i < 8; ++i) {
        int n = nbase + mb + i;
        if (n < N) {
            Y[n * HDIM + c]      = acc[i][0];
            Y[n * HDIM + c + 64] = acc[i][1];
        }
    }
}

__global__ void gemm12_kernel(const float* __restrict__ X, const float* __restrict__ W2,
                              float* __restrict__ Y, int N)
{
    int idx = blockIdx.x * 256 + threadIdx.x;
    int n = idx / ODIM, c = idx - n * ODIM;
    if (n >= N) return;
    float acc = 0.f;
    for (int k = 0; k < 128; ++k) acc = fmaf(X[n * HDIM + k], W2[k * ODIM + c], acc);
    Y[n * ODIM + c] = acc;
}

__global__ __launch_bounds__(128) void agg128_kernel(const float* __restrict__ hW,
        const int* __restrict__ row_ptr, const int* __restrict__ degi,
        const int* __restrict__ csr_src, const float* __restrict__ dinv,
        const float* __restrict__ bias, float* __restrict__ out, int N, int do_relu)
{
    int n = blockIdx.x;
    int c = threadIdx.x;
    float dn = dinv[n];
    float acc = hW[n * HDIM + c] * dn * dn;
    int start = row_ptr[n];
    int cnt = degi[n];
    for (int i = 0; i < cnt; ++i) {
        int s = csr_src[start + i];
        acc = fmaf(hW[s * HDIM + c], dinv[s] * dn, acc);
    }
    float v = acc + bias[c];
    if (do_relu) v = fmaxf(v, 0.f);
    out[n * HDIM + c] = v;
}

__global__ void agg12_kernel(const float* __restrict__ hW, const int* __restrict__ row_ptr,
        const int* __restrict__ degi, const int* __restrict__ csr_src,
        const float* __restrict__ dinv, const float* __restrict__ b2,
        float* __restrict__ out, int N)
{
    int idx = blockIdx.x * 256 + threadIdx.x;
    int n = idx / ODIM, c = idx - n * ODIM;
    if (n >= N) return;
    float dn = dinv[n];
    float acc = hW[n * ODIM + c] * dn * dn;
    int start = row_ptr[n], cnt = degi[n];
    for (int i = 0; i < cnt; ++i) {
        int s = csr_src[start + i];
        acc = fmaf(hW[s * ODIM + c], dinv[s] * dn, acc);
    }
    out[n * ODIM + c] = acc + b2[c];
}

extern "C" void kernel_launch(void* const* d_in, const int* in_sizes, int n_in,
                              void* d_out, int out_size, void* d_ws, size_t ws_size,
                              hipStream_t stream)
{
    const float* x     = (const float*)d_in[0];
    const int*   ei    = (const int*)d_in[1];
    const float* Wih0  = (const float*)d_in[2];
    const float* Whh0  = (const float*)d_in[3];
    const float* bih0  = (const float*)d_in[4];
    const float* bhh0  = (const float*)d_in[5];
    const float* Wih1  = (const float*)d_in[6];
    const float* Whh1  = (const float*)d_in[7];
    const float* bih1  = (const float*)d_in[8];
    const float* bhh1  = (const float*)d_in[9];
    const float* W0    = (const float*)d_in[10];
    const float* b0    = (const float*)d_in[11];
    const float* W1    = (const float*)d_in[12];
    const float* b1    = (const float*)d_in[13];
    const float* W2    = (const float*)d_in[14];
    const float* b2    = (const float*)d_in[15];
    float* out = (float*)d_out;

    const int N = in_sizes[0] / (TT * 2);
    const int E = in_sizes[1] / 2;

    unsigned short* Wpk = (unsigned short*)d_ws;          // 384 KB
    float* fbase = (float*)((char*)d_ws + 393216);
    float* hbuf = fbase;                                  // N*128
    float* buf1 = hbuf + (size_t)N * HDIM;                // N*128
    float* buf2 = buf1 + (size_t)N * HDIM;                // N*128
    float* dinv = buf2 + (size_t)N * HDIM;                // N
    int* degi    = (int*)(dinv + N);                      // N
    int* fill    = degi + N;                              // N
    int* counter = fill + N;                              // 1
    int* row_ptr = counter + 1;                           // N
    int* csr_src = row_ptr + N;                           // E

    hipMemsetAsync(degi, 0, (size_t)(2 * N + 1) * sizeof(int), stream);

    pack_kernel<<<(384 * 64 + 255) / 256, 256, 0, stream>>>(Whh0, Wih1, Whh1, Wpk);

    lstm_mfma_kernel<<<(N + MBX - 1) / MBX, 256, 0, stream>>>(
        x, Wpk, Wih0, bih0, bhh0, bih1, bhh1, hbuf, N);

    deg_count_kernel<<<(E + 255) / 256, 256, 0, stream>>>(ei, degi, E);
    row_alloc_kernel<<<(N + 255) / 256, 256, 0, stream>>>(degi, row_ptr, dinv, counter, N);
    csr_fill_kernel<<<(E + 255) / 256, 256, 0, stream>>>(ei, row_ptr, fill, csr_src, E);

    gemm128_kernel<<<(N + 31) / 32, 256, 0, stream>>>(hbuf, W0, buf1, N);
    agg128_kernel<<<N, 128, 0, stream>>>(buf1, row_ptr, degi, csr_src, dinv, b0, buf2, N, 1);
    gemm128_kernel<<<(N + 31) / 32, 256, 0, stream>>>(buf2, W1, buf1, N);
    agg128_kernel<<<N, 128, 0, stream>>>(buf1, row_ptr, degi, csr_src, dinv, b1, buf2, N, 1);
    gemm12_kernel<<<((size_t)N * ODIM + 255) / 256, 256, 0, stream>>>(buf2, W2, buf1, N);
    agg12_kernel<<<((size_t)N * ODIM + 255) / 256, 256, 0, stream>>>(
        buf1, row_ptr, degi, csr_src, dinv, b2, out, N);
}

// Round 7
// 1458.687 us; speedup vs baseline: 1.4118x; 1.4118x over previous
//
#include <hip/hip_runtime.h>
#include <hip/hip_bf16.h>

#define TT 12
#define HDIM 128
#define ODIM 12
#define KS0 136        // LDS h-row stride in shorts (272 B; 0 bank conflicts measured in R4)
#define KS1 136
#define TPAD 36        // fp32 GCN gemm LDS pad

typedef short bf16x8 __attribute__((ext_vector_type(8)));
typedef float f32x16 __attribute__((ext_vector_type(16)));

__device__ __forceinline__ float fastrcp(float x) { return __builtin_amdgcn_rcpf(x); }
__device__ __forceinline__ float sigf(float x) { return fastrcp(1.f + __expf(-x)); }
__device__ __forceinline__ float tanh_fast(float x) { return 1.f - 2.f * fastrcp(1.f + __expf(2.f * x)); }
__device__ __forceinline__ unsigned short f2bf(float f) {
    union { float f; unsigned int u; } v; v.f = f;
    unsigned int r = v.u + 0x7FFFu + ((v.u >> 16) & 1u);
    return (unsigned short)(r >> 16);
}

// ---------------- weight pre-pack into MFMA B-fragment order ----------------
// K=128 for all 3 matrices. slot = (mat*16 + cb)*8 + s  (384 slots x 1 KB = 384 KB)
// element = Wpk[(slot*64 + lane)*8 + j];  B[k][col]: col=cb*32+(lane&31), k=s*16+(lane>>5)*8+j
__global__ void pack_kernel(const float* __restrict__ Whh0, const float* __restrict__ Wih1,
                            const float* __restrict__ Whh1, unsigned short* __restrict__ Wpk)
{
    int idx = blockIdx.x * 256 + threadIdx.x;
    if (idx >= 384 * 64) return;
    int lane = idx & 63;
    int slot = idx >> 6;
    int mat = slot >> 7;
    int rem = slot & 127;
    int cb = rem >> 3, s = rem & 7;
    int col = cb * 32 + (lane & 31);
    const float* src = (mat == 0) ? Whh0 : (mat == 1) ? Wih1 : Whh1;
#pragma unroll
    for (int j = 0; j < 8; ++j) {
        int k = s * 16 + ((lane >> 5) << 3) + j;
        Wpk[((size_t)(slot * 64 + lane) << 3) + j] = f2bf(src[col * 128 + k]);
    }
}

// ---------------- L0: layer-0 LSTM, Whh0 resident in LDS, persistent blocks ----------------
// 512 thr = 8 waves; wave: rb = w>>2 (node half of 64-tile), wsub = w&3 (channel group).
// acc[4] = 64 AGPR; c0[16] regs. Zero weight restream.
__global__ __launch_bounds__(512, 1) void lstm_l0_kernel(
    const float* __restrict__ x,              // [N][12][2]
    const unsigned short* __restrict__ Wpk,   // mat0 = Whh0 packed (128 KB)
    const float* __restrict__ Wih0,           // [512][2]
    const float* __restrict__ bih0, const float* __restrict__ bhh0,
    unsigned short* __restrict__ h0seq,       // [N][12][128] bf16 out
    int N, int ntiles)
{
    __shared__ unsigned short wlds[65536];    // 128 KB
    __shared__ unsigned short hA0[64 * KS0];  // 17.4 KB
    __shared__ float xls[64 * 24];            // 6 KB

    const int tid  = threadIdx.x;
    const int w    = tid >> 6;
    const int ln   = tid & 63;
    const int ln31 = ln & 31;
    const int half = ln >> 5;
    const int wsub = w & 3;
    const int rb   = w >> 2;                  // 0/1
    const int col  = wsub * 32 + ln31;

    // load Whh0 fragments into LDS once per block (coalesced b128)
    for (int i = tid * 8; i < 65536; i += 512 * 8)
        *(bf16x8*)(wlds + i) = *(const bf16x8*)(Wpk + i);

    // per-thread layer-0 gate constants
    float wx0[4], wx1[4], br0[4];
#pragma unroll
    for (int g = 0; g < 4; ++g) {
        int row = (g << 7) + col;
        wx0[g] = Wih0[row * 2 + 0];
        wx1[g] = Wih0[row * 2 + 1];
        br0[g] = bih0[row] + bhh0[row];
    }

    for (int tile = blockIdx.x; tile < ntiles; tile += gridDim.x) {
        const int nbase = tile * 64;
        __syncthreads();                       // prev tile fully done before restage
        for (int i = tid; i < 64 * 24; i += 512) {
            int n = nbase + i / 24;
            xls[i] = (n < N) ? x[nbase * 24 + i] : 0.f;
        }
        for (int i = tid; i < 64 * KS0; i += 512) hA0[i] = 0;
        float c0[16];
#pragma unroll
        for (int r = 0; r < 16; ++r) c0[r] = 0.f;
        __syncthreads();

        for (int t = 0; t < TT; ++t) {
            f32x16 acc[4];
#pragma unroll
            for (int g = 0; g < 4; ++g)
#pragma unroll
                for (int e = 0; e < 16; ++e) acc[g][e] = 0.f;
#pragma unroll
            for (int s = 0; s < 8; ++s) {
                bf16x8 a = *(const bf16x8*)(hA0 + (rb * 32 + ln31) * KS0 + s * 16 + half * 8);
#pragma unroll
                for (int g = 0; g < 4; ++g) {
                    int cb = g * 4 + wsub;
                    bf16x8 b = *(const bf16x8*)(wlds + (((cb * 8 + s) * 64 + ln) << 3));
                    acc[g] = __builtin_amdgcn_mfma_f32_32x32x16_bf16(a, b, acc[g], 0, 0, 0);
                }
            }
            __syncthreads();                   // B1: hA0 reads done
#pragma unroll
            for (int r = 0; r < 16; ++r) {
                int node = rb * 32 + (r & 3) + 8 * (r >> 2) + 4 * half;
                float xa = xls[node * 24 + t * 2 + 0];
                float xb = xls[node * 24 + t * 2 + 1];
                float zi = acc[0][r] + br0[0] + wx0[0] * xa + wx1[0] * xb;
                float zf = acc[1][r] + br0[1] + wx0[1] * xa + wx1[1] * xb;
                float zg = acc[2][r] + br0[2] + wx0[2] * xa + wx1[2] * xb;
                float zo = acc[3][r] + br0[3] + wx0[3] * xa + wx1[3] * xb;
                float cn = sigf(zf) * c0[r] + sigf(zi) * tanh_fast(zg);
                c0[r] = cn;
                float h = sigf(zo) * tanh_fast(cn);
                unsigned short us = f2bf(h);
                hA0[node * KS0 + col] = us;
                int n = nbase + node;
                if (n < N) h0seq[(n * TT + t) * HDIM + col] = us;
            }
            __syncthreads();                   // B2: h0_t visible
        }
    }
}

// ---------------- L1: layer-1 LSTM, weights streamed, spill-free ----------------
// 512 thr = 8 waves; wave: rbb = (w>>2)*2 (two row-blocks), wsub = w&3.
// acc[2][4] = 128 AGPR; arch state: c1[2][16] + bias only.
__global__ __launch_bounds__(512, 1) void lstm_l1_kernel(
    const unsigned short* __restrict__ h0seq, // [N][12][128] bf16
    const unsigned short* __restrict__ Wpk,   // mat1 = Wih1 @ +65536, mat2 = Whh1 @ +131072
    const float* __restrict__ bih1, const float* __restrict__ bhh1,
    float* __restrict__ hbuf,                 // [N][128] fp32 out
    int N)
{
    __shared__ unsigned short hA1[128 * KS1]; // 34.8 KB

    const int tid  = threadIdx.x;
    const int w    = tid >> 6;
    const int ln   = tid & 63;
    const int ln31 = ln & 31;
    const int half = ln >> 5;
    const int wsub = w & 3;
    const int rbb  = (w >> 2) << 1;           // 0 or 2
    const int col  = wsub * 32 + ln31;
    const int nbase = blockIdx.x * 128;

    float br1[4];
#pragma unroll
    for (int g = 0; g < 4; ++g) {
        int row = (g << 7) + col;
        br1[g] = bih1[row] + bhh1[row];
    }

    for (int i = tid; i < 128 * KS1; i += 512) hA1[i] = 0;

    float c1[2][16];
#pragma unroll
    for (int rbi = 0; rbi < 2; ++rbi)
#pragma unroll
        for (int r = 0; r < 16; ++r) c1[rbi][r] = 0.f;

    __syncthreads();

    const unsigned short* Wm1 = Wpk + 65536;
    const unsigned short* Wm2 = Wpk + 131072;
    const bf16x8 zv = {0, 0, 0, 0, 0, 0, 0, 0};

    for (int t = 0; t < TT; ++t) {
        f32x16 acc[2][4];
#pragma unroll
        for (int rbi = 0; rbi < 2; ++rbi)
#pragma unroll
            for (int g = 0; g < 4; ++g)
#pragma unroll
                for (int e = 0; e < 16; ++e) acc[rbi][g][e] = 0.f;

#pragma unroll
        for (int s = 0; s < 8; ++s) {
            bf16x8 a0[2], a1[2];
#pragma unroll
            for (int rbi = 0; rbi < 2; ++rbi) {
                int node = (rbb + rbi) * 32 + ln31;
                int n = nbase + node;
                a0[rbi] = (n < N)
                    ? *(const bf16x8*)(h0seq + (n * TT + t) * HDIM + s * 16 + half * 8)
                    : zv;
                a1[rbi] = *(const bf16x8*)(hA1 + node * KS1 + s * 16 + half * 8);
            }
#pragma unroll
            for (int g = 0; g < 4; ++g) {
                int cb = g * 4 + wsub;
                bf16x8 b1 = *(const bf16x8*)(Wm1 + (((cb * 8 + s) * 64 + ln) << 3));
                bf16x8 b2 = *(const bf16x8*)(Wm2 + (((cb * 8 + s) * 64 + ln) << 3));
#pragma unroll
                for (int rbi = 0; rbi < 2; ++rbi) {
                    acc[rbi][g] = __builtin_amdgcn_mfma_f32_32x32x16_bf16(a0[rbi], b1, acc[rbi][g], 0, 0, 0);
                    acc[rbi][g] = __builtin_amdgcn_mfma_f32_32x32x16_bf16(a1[rbi], b2, acc[rbi][g], 0, 0, 0);
                }
            }
        }
        __syncthreads();                       // B1: hA1 reads done

#pragma unroll
        for (int rbi = 0; rbi < 2; ++rbi) {
#pragma unroll
            for (int r = 0; r < 16; ++r) {
                int node = (rbb + rbi) * 32 + (r & 3) + 8 * (r >> 2) + 4 * half;
                float zi = acc[rbi][0][r] + br1[0];
                float zf = acc[rbi][1][r] + br1[1];
                float zg = acc[rbi][2][r] + br1[2];
                float zo = acc[rbi][3][r] + br1[3];
                float cn = sigf(zf) * c1[rbi][r] + sigf(zi) * tanh_fast(zg);
                c1[rbi][r] = cn;
                float h = sigf(zo) * tanh_fast(cn);
                if (t + 1 < TT) {
                    hA1[node * KS1 + col] = f2bf(h);
                } else {
                    int n = nbase + node;
                    if (n < N) hbuf[n * HDIM + col] = h;
                }
            }
        }
        __syncthreads();                       // B2: h1_t visible
    }
}

// ---------------- GCN (unchanged) ----------------
__global__ void deg_count_kernel(const int* __restrict__ ei, int* __restrict__ degi, int E)
{
    int e = blockIdx.x * 256 + threadIdx.x;
    if (e < E) atomicAdd(&degi[ei[E + e]], 1);
}

__global__ void row_alloc_kernel(const int* __restrict__ degi, int* __restrict__ row_ptr,
                                 float* __restrict__ dinv, int* __restrict__ counter, int N)
{
    int n = blockIdx.x * 256 + threadIdx.x;
    int lane = threadIdx.x & 63;
    int v = (n < N) ? degi[n] : 0;
    int incl = v;
    for (int off = 1; off < 64; off <<= 1) {
        int u = __shfl_up(incl, off);
        if (lane >= off) incl += u;
    }
    int base = 0;
    if (lane == 63) base = atomicAdd(counter, incl);
    base = __shfl(base, 63);
    if (n < N) {
        row_ptr[n] = base + (incl - v);
        dinv[n] = rsqrtf((float)(v + 1));
    }
}

__global__ void csr_fill_kernel(const int* __restrict__ ei, const int* __restrict__ row_ptr,
                                int* __restrict__ fill, int* __restrict__ csr_src, int E)
{
    int e = blockIdx.x * 256 + threadIdx.x;
    if (e < E) {
        int d = ei[E + e];
        int p = atomicAdd(&fill[d], 1);
        csr_src[row_ptr[d] + p] = ei[e];
    }
}

__global__ __launch_bounds__(256) void gemm128_kernel(const float* __restrict__ X,
                                                      const float* __restrict__ W,
                                                      float* __restrict__ Y, int N)
{
    __shared__ float XT[128 * TPAD];
    const int tid = threadIdx.x;
    const int nbase = blockIdx.x * 32;
    for (int idx = tid; idx < 32 * 128; idx += 256) {
        int m = idx >> 7, k = idx & 127;
        int n = nbase + m;
        XT[k * TPAD + m] = (n < N) ? X[n * HDIM + k] : 0.f;
    }
    __syncthreads();
    const int c  = tid & 63;
    const int mb = (tid >> 6) << 3;
    float acc[8][2];
#pragma unroll
    for (int i = 0; i < 8; ++i) { acc[i][0] = 0.f; acc[i][1] = 0.f; }
    for (int k = 0; k < 128; ++k) {
        const float* xr = &XT[k * TPAD + mb];
        float4 a0 = *(const float4*)(xr);
        float4 a1 = *(const float4*)(xr + 4);
        float a[8] = {a0.x, a0.y, a0.z, a0.w, a1.x, a1.y, a1.z, a1.w};
        float b0 = W[k * HDIM + c];
        float b1 = W[k * HDIM + c + 64];
#pragma unroll
        for (int i = 0; i < 8; ++i) {
            acc[i][0] = fmaf(a[i], b0, acc[i][0]);
            acc[i][1] = fmaf(a[i], b1, acc[i][1]);
        }
    }
#pragma unroll
    for (int i = 0; i < 8; ++i) {
        int n = nbase + mb + i;
        if (n < N) {
            Y[n * HDIM + c]      = acc[i][0];
            Y[n * HDIM + c + 64] = acc[i][1];
        }
    }
}

__global__ void gemm12_kernel(const float* __restrict__ X, const float* __restrict__ W2,
                              float* __restrict__ Y, int N)
{
    int idx = blockIdx.x * 256 + threadIdx.x;
    int n = idx / ODIM, c = idx - n * ODIM;
    if (n >= N) return;
    float acc = 0.f;
    for (int k = 0; k < 128; ++k) acc = fmaf(X[n * HDIM + k], W2[k * ODIM + c], acc);
    Y[n * ODIM + c] = acc;
}

__global__ __launch_bounds__(128) void agg128_kernel(const float* __restrict__ hW,
        const int* __restrict__ row_ptr, const int* __restrict__ degi,
        const int* __restrict__ csr_src, const float* __restrict__ dinv,
        const float* __restrict__ bias, float* __restrict__ out, int N, int do_relu)
{
    int n = blockIdx.x;
    int c = threadIdx.x;
    float dn = dinv[n];
    float acc = hW[n * HDIM + c] * dn * dn;
    int start = row_ptr[n];
    int cnt = degi[n];
    for (int i = 0; i < cnt; ++i) {
        int s = csr_src[start + i];
        acc = fmaf(hW[s * HDIM + c], dinv[s] * dn, acc);
    }
    float v = acc + bias[c];
    if (do_relu) v = fmaxf(v, 0.f);
    out[n * HDIM + c] = v;
}

__global__ void agg12_kernel(const float* __restrict__ hW, const int* __restrict__ row_ptr,
        const int* __restrict__ degi, const int* __restrict__ csr_src,
        const float* __restrict__ dinv, const float* __restrict__ b2,
        float* __restrict__ out, int N)
{
    int idx = blockIdx.x * 256 + threadIdx.x;
    int n = idx / ODIM, c = idx - n * ODIM;
    if (n >= N) return;
    float dn = dinv[n];
    float acc = hW[n * ODIM + c] * dn * dn;
    int start = row_ptr[n], cnt = degi[n];
    for (int i = 0; i < cnt; ++i) {
        int s = csr_src[start + i];
        acc = fmaf(hW[s * ODIM + c], dinv[s] * dn, acc);
    }
    out[n * ODIM + c] = acc + b2[c];
}

extern "C" void kernel_launch(void* const* d_in, const int* in_sizes, int n_in,
                              void* d_out, int out_size, void* d_ws, size_t ws_size,
                              hipStream_t stream)
{
    const float* x     = (const float*)d_in[0];
    const int*   ei    = (const int*)d_in[1];
    const float* Wih0  = (const float*)d_in[2];
    const float* Whh0  = (const float*)d_in[3];
    const float* bih0  = (const float*)d_in[4];
    const float* bhh0  = (const float*)d_in[5];
    const float* Wih1  = (const float*)d_in[6];
    const float* Whh1  = (const float*)d_in[7];
    const float* bih1  = (const float*)d_in[8];
    const float* bhh1  = (const float*)d_in[9];
    const float* W0    = (const float*)d_in[10];
    const float* b0    = (const float*)d_in[11];
    const float* W1    = (const float*)d_in[12];
    const float* b1    = (const float*)d_in[13];
    const float* W2    = (const float*)d_in[14];
    const float* b2    = (const float*)d_in[15];
    float* out = (float*)d_out;

    const int N = in_sizes[0] / (TT * 2);
    const int E = in_sizes[1] / 2;

    // ---- workspace layout ----
    unsigned short* Wpk = (unsigned short*)d_ws;          // 384 KB
    float* fbase = (float*)((char*)d_ws + 393216);
    float* hbuf = fbase;                                  // N*128 fp32
    float* buf1 = hbuf + (size_t)N * HDIM;                // N*128
    float* buf2 = buf1 + (size_t)N * HDIM;                // N*128
    float* dinv = buf2 + (size_t)N * HDIM;                // N
    int* degi    = (int*)(dinv + N);                      // N
    int* fill    = degi + N;                              // N
    int* counter = fill + N;                              // 1
    int* row_ptr = counter + 1;                           // N
    int* csr_src = row_ptr + N;                           // E
    // 16B-aligned bf16 h0 sequence [N][12][128]  (+153.6 MB)
    size_t off = ((size_t)(csr_src + E) - (size_t)d_ws + 15) & ~(size_t)15;
    unsigned short* h0seq = (unsigned short*)((char*)d_ws + off);

    hipMemsetAsync(degi, 0, (size_t)(2 * N + 1) * sizeof(int), stream);

    pack_kernel<<<(384 * 64 + 255) / 256, 256, 0, stream>>>(Whh0, Wih1, Whh1, Wpk);

    const int ntiles = (N + 63) / 64;
    lstm_l0_kernel<<<256, 512, 0, stream>>>(x, Wpk, Wih0, bih0, bhh0, h0seq, N, ntiles);
    lstm_l1_kernel<<<(N + 127) / 128, 512, 0, stream>>>(h0seq, Wpk, bih1, bhh1, hbuf, N);

    deg_count_kernel<<<(E + 255) / 256, 256, 0, stream>>>(ei, degi, E);
    row_alloc_kernel<<<(N + 255) / 256, 256, 0, stream>>>(degi, row_ptr, dinv, counter, N);
    csr_fill_kernel<<<(E + 255) / 256, 256, 0, stream>>>(ei, row_ptr, fill, csr_src, E);

    gemm128_kernel<<<(N + 31) / 32, 256, 0, stream>>>(hbuf, W0, buf1, N);
    agg128_kernel<<<N, 128, 0, stream>>>(buf1, row_ptr, degi, csr_src, dinv, b0, buf2, N, 1);
    gemm128_kernel<<<(N + 31) / 32, 256, 0, stream>>>(buf2, W1, buf1, N);
    agg128_kernel<<<N, 128, 0, stream>>>(buf1, row_ptr, degi, csr_src, dinv, b1, buf2, N, 1);
    gemm12_kernel<<<((size_t)N * ODIM + 255) / 256, 256, 0, stream>>>(buf2, W2, buf1, N);
    agg12_kernel<<<((size_t)N * ODIM + 255) / 256, 256, 0, stream>>>(
        buf1, row_ptr, degi, csr_src, dinv, b2, out, N);
}